// Round 8
// baseline (478.628 us; speedup 1.0000x reference)
//
#include <hip/hip_runtime.h>
#include <hip/hip_bf16.h>
#include <cstddef>

// Problem constants
constexpr int B_  = 2;
constexpr int T_  = 8;
constexpr int HW_ = 37;          // H == W == 37
constexpr int N_  = HW_ * HW_;   // 1369
constexpr int C_  = 384;
constexpr int NH_ = 8;
constexpr int MP_ = 8;
constexpr int HD_ = C_ / NH_;    // 48
constexpr int M_  = B_ * T_ * N_; // 21904

typedef short bf16x8 __attribute__((ext_vector_type(8)));
typedef float f32x4 __attribute__((ext_vector_type(4)));
typedef float f32x2 __attribute__((ext_vector_type(2)));
typedef unsigned u32x3 __attribute__((ext_vector_type(3)));
// reduced-alignment typedefs for gather loads (addresses are 8B-aligned)
typedef f32x4 uaf32x4 __attribute__((aligned(8)));
typedef u32x3 uau32x3 __attribute__((aligned(4)));

static __device__ __forceinline__ unsigned short bf16_bits(float v) {
  __hip_bfloat16 b = __float2bfloat16(v);
  return *reinterpret_cast<unsigned short*>(&b);
}

static __device__ __forceinline__ f32x2 unpk(unsigned u) {
  f32x2 r;
  r.x = __uint_as_float(u << 16);
  r.y = __uint_as_float(u & 0xffff0000u);
  return r;
}

// ---------------------------------------------------------------------------
// Fused cast + transpose. One pass over f (fp32 [B,T,N,C]):
//   A16[b][t][n][c] = bf16(f)     (same layout, feeds GEMM1)
//   ft [b][n][t][c] = f  (fp32)   (T adjacent to C, feeds attend — no unpack)
// ---------------------------------------------------------------------------
__global__ __launch_bounds__(256)
void cast_transpose_kernel(const float* __restrict__ f,
                           __hip_bfloat16* __restrict__ A16,
                           float* __restrict__ ft) {
  const int bn = blockIdx.x;          // b*N + n
  const int n = bn % N_;
  const int b = bn / N_;
  const size_t dst_base = (size_t)bn * (T_ * C_);
#pragma unroll
  for (int i = 0; i < 12; ++i) {      // 12*256 = 3072 = T*C
    int idx = i * 256 + threadIdx.x;  // t*C + c
    int t = idx / C_;
    int c = idx - t * C_;
    size_t src = ((size_t)(b * T_ + t) * N_ + n) * C_ + c;
    float v = f[src];
    ft[dst_base + idx] = v;
    A16[src] = __float2bfloat16(v);
  }
}

// ---------------------------------------------------------------------------
// Pre-transpose weights to [N][K] bf16.
// ---------------------------------------------------------------------------
__global__ __launch_bounds__(256)
void prep_w_kernel(const float* __restrict__ Wq, const float* __restrict__ Woff,
                   const float* __restrict__ Wout,
                   __hip_bfloat16* __restrict__ Wt, __hip_bfloat16* __restrict__ Wot) {
  int nrow = blockIdx.x;           // 0..895
  if (nrow < 512) {
    const float* src; int col, ld;
    if (nrow < 384) { src = Wq; col = nrow; ld = 384; }
    else            { src = Woff; col = nrow - 384; ld = 128; }
    for (int k = threadIdx.x; k < 384; k += 256)
      Wt[(size_t)nrow * 384 + k] = __float2bfloat16(src[(size_t)k * ld + col]);
  } else {
    int col = nrow - 512;
    for (int k = threadIdx.x; k < 384; k += 256)
      Wot[(size_t)col * 384 + k] = __float2bfloat16(Wout[(size_t)k * 384 + col]);
  }
}

// ---------------------------------------------------------------------------
// bf16 MFMA GEMM: acc = A[M,384] @ Wt[N,384]^T + bias, scaled by out0_scale.
// split=1 (GEMM1): N=512; cols<384 -> out0h (bf16, scaled), cols>=384 -> out1 (fp32).
// split=0 (GEMM2): out0 (fp32).
// ---------------------------------------------------------------------------
__global__ __launch_bounds__(256)
void mfma_gemm_kernel(const __hip_bfloat16* __restrict__ A,
                      const __hip_bfloat16* __restrict__ Wt,
                      const float* __restrict__ b0, const float* __restrict__ b1,
                      float* __restrict__ out0, __hip_bfloat16* __restrict__ out0h,
                      float* __restrict__ out1,
                      int split, float out0_scale) {
  __shared__ __hip_bfloat16 As[128][40];
  __shared__ __hip_bfloat16 Bs[128][40];
  const int m0 = blockIdx.x * 128;
  const int n0 = blockIdx.y * 128;
  const int tid = threadIdx.x;
  const int wv = tid >> 6, lane = tid & 63;
  const int wr = wv >> 1, wc = wv & 1;
  const int lr = lane & 15, kg = lane >> 4;

  f32x4 acc[4][4] = {};

  for (int k0 = 0; k0 < 384; k0 += 32) {
#pragma unroll
    for (int u = 0; u < 2; ++u) {
      int c = tid + u * 256;
      int row = c >> 2;
      int off = (c & 3) * 8;
      int gm = m0 + row;
      uint4 va = make_uint4(0u, 0u, 0u, 0u);
      if (gm < M_) va = *(const uint4*)(A + (size_t)gm * 384 + k0 + off);
      *(uint4*)&As[row][off] = va;
      uint4 vb = *(const uint4*)(Wt + (size_t)(n0 + row) * 384 + k0 + off);
      *(uint4*)&Bs[row][off] = vb;
    }
    __syncthreads();

    bf16x8 af[4], bfr[4];
#pragma unroll
    for (int i = 0; i < 4; ++i)
      af[i] = *(const bf16x8*)&As[wr * 64 + i * 16 + lr][kg * 8];
#pragma unroll
    for (int i = 0; i < 4; ++i)
      bfr[i] = *(const bf16x8*)&Bs[wc * 64 + i * 16 + lr][kg * 8];

#pragma unroll
    for (int mi = 0; mi < 4; ++mi)
#pragma unroll
      for (int ni = 0; ni < 4; ++ni)
        acc[mi][ni] = __builtin_amdgcn_mfma_f32_16x16x32_bf16(
            af[mi], bfr[ni], acc[mi][ni], 0, 0, 0);
    __syncthreads();
  }

  const int mrow = (lane >> 4) * 4;
#pragma unroll
  for (int mi = 0; mi < 4; ++mi) {
#pragma unroll
    for (int ni = 0; ni < 4; ++ni) {
#pragma unroll
      for (int j = 0; j < 4; ++j) {
        int gm = m0 + wr * 64 + mi * 16 + mrow + j;
        int gn = n0 + wc * 64 + ni * 16 + lr;
        if (gm >= M_) continue;
        float v = acc[mi][ni][j];
        if (!split) {
          out0[(size_t)gm * 384 + gn] = (v + b0[gn]) * out0_scale;
        } else {
          if (gn < 384) out0h[(size_t)gm * 384 + gn] =
              __float2bfloat16((v + b0[gn]) * out0_scale);
          else          out1[(size_t)gm * 128 + (gn - 384)] = v + b1[gn - 384];
        }
      }
    }
  }
}

// ---------------------------------------------------------------------------
// Deformable attention core (fp32 ft — zero unpack in the inner loop).
// Grid = (bn, head-quad) = 5476 blocks (XCD-chunked bijective swizzle);
// 4 waves/block, ONE head per wave, t-loop inside (L2 reuse of ft).
// Lane role: p = lane>>3 (point), k = lane&7 (channel slice d = 6k..6k+5).
// Softmax without max-sub (logits O(1), masked -> e=0). Packed f32 math.
// log2e/sqrt(48) folded into Q upstream (bf16); 1/T folded into final store.
// ---------------------------------------------------------------------------
__global__ __launch_bounds__(256)
void attend_kernel(const float* __restrict__ ft,
                   const __hip_bfloat16* __restrict__ Qb,
                   const float* __restrict__ OFF,
                   __hip_bfloat16* __restrict__ O1) {
  // bijective chunked XCD swizzle over grid of B*N*2 = 5476 blocks
  const int grid = B_ * N_ * 2;
  const int q8 = grid / 8, r8 = grid % 8;
  int c = blockIdx.x & 7, j = blockIdx.x >> 3;
  int id = (c < r8) ? c * (q8 + 1) + j : r8 * (q8 + 1) + (c - r8) * q8 + j;
  const int hq = id & 1;
  const int bn = id >> 1;

  const int n = bn % N_;
  const int b = bn / N_;
  const int w    = threadIdx.x >> 6;
  const int h    = hq * 4 + w;          // one head per wave
  const int lane = threadIdx.x & 63;
  const int p = lane >> 3;
  const int k = lane & 7;
  const float cy = (float)(n / HW_);
  const float cx = (float)(n % HW_);
  const int bnb = b * N_;
  const int chb = h * HD_ + 6 * k;

  for (int t = 0; t < T_; ++t) {
    const size_t row = (size_t)(b * T_ + t) * N_ + n;

    // q fragment (bf16, pre-scaled by log2e/sqrt(48) in GEMM epilogue)
    uau32x3 qw = *(const uau32x3*)(Qb + row * C_ + h * HD_ + 6 * k);
    f32x2 q01 = unpk(qw.x), q23 = unpk(qw.y), q45 = unpk(qw.z);

    // bilinear taps for my point p
    const float* op = OFF + row * (NH_ * MP_ * 2) + h * (MP_ * 2) + p * 2;
    float y = cy + op[0];
    float x = cx + op[1];
    float y0f = floorf(y), x0f = floorf(x);
    float wy = y - y0f, wx = x - x0f;
    int y0 = (int)y0f, x0 = (int)x0f;
    int y1 = y0 + 1, x1 = x0 + 1;
    float vy0 = (y0 >= 0 && y0 < HW_) ? 1.f : 0.f;
    float vy1 = (y1 >= 0 && y1 < HW_) ? 1.f : 0.f;
    float vx0 = (x0 >= 0 && x0 < HW_) ? 1.f : 0.f;
    float vx1 = (x1 >= 0 && x1 < HW_) ? 1.f : 0.f;
    int cy0 = min(max(y0, 0), HW_ - 1), cy1 = min(max(y1, 0), HW_ - 1);
    int cx0 = min(max(x0, 0), HW_ - 1), cx1 = min(max(x1, 0), HW_ - 1);
    float tw0 = (1.f - wy) * (1.f - wx) * vy0 * vx0;
    float tw1 = (1.f - wy) * wx * vy0 * vx1;
    float tw2 = wy * (1.f - wx) * vy1 * vx0;
    float tw3 = wy * wx * vy1 * vx1;
    f32x4 tw04 = {tw0, tw0, tw0, tw0}, tw14 = {tw1, tw1, tw1, tw1};
    f32x4 tw24 = {tw2, tw2, tw2, tw2}, tw34 = {tw3, tw3, tw3, tw3};
    f32x2 tw02 = {tw0, tw0}, tw12 = {tw1, tw1}, tw22 = {tw2, tw2}, tw32 = {tw3, tw3};

    // float-element bases for the 4 taps
    const float* tp0 = ft + ((bnb + cy0 * HW_ + cx0) * T_) * C_ + chb;
    const float* tp1 = ft + ((bnb + cy0 * HW_ + cx1) * T_) * C_ + chb;
    const float* tp2 = ft + ((bnb + cy1 * HW_ + cx0) * T_) * C_ + chb;
    const float* tp3 = ft + ((bnb + cy1 * HW_ + cx1) * T_) * C_ + chb;

    f32x4 oa0123 = {0.f, 0.f, 0.f, 0.f};
    f32x2 oa45 = {0.f, 0.f};

#pragma unroll
    for (int r = 0; r < T_; ++r) {
      const int roff = r * C_;
      f32x4 a4 = *(const uaf32x4*)(tp0 + roff);
      f32x2 a2 = *(const f32x2*)(tp0 + roff + 4);
      f32x4 b4 = *(const uaf32x4*)(tp1 + roff);
      f32x2 b2 = *(const f32x2*)(tp1 + roff + 4);
      f32x4 c4 = *(const uaf32x4*)(tp2 + roff);
      f32x2 c2 = *(const f32x2*)(tp2 + roff + 4);
      f32x4 d4 = *(const uaf32x4*)(tp3 + roff);
      f32x2 d2 = *(const f32x2*)(tp3 + roff + 4);

      f32x4 s0123 = a4 * tw04 + b4 * tw14 + c4 * tw24 + d4 * tw34;
      f32x2 s45   = a2 * tw02 + b2 * tw12 + c2 * tw22 + d2 * tw32;

      // logit: packed dot + horizontal add, then k-group reduce (xor 1,2,4)
      f32x2 lg2 = q01 * s0123.lo + q23 * s0123.hi + q45 * s45;
      float lg = lg2.x + lg2.y;
      lg += __shfl_xor(lg, 1);
      lg += __shfl_xor(lg, 2);
      lg += __shfl_xor(lg, 4);

      // point-count mask for this (t, r)
      int dd = t - r; dd = dd < 0 ? -dd : dd;
      int npts = (56 - 8 * dd) / 7; npts = npts < 1 ? 1 : npts;

      // softmax over p without max-sub (logits O(1); masked -> 0)
      float e = (p < npts) ? exp2f(lg) : 0.f;
      float ssum = e;
      ssum += __shfl_xor(ssum, 8);
      ssum += __shfl_xor(ssum, 16);
      ssum += __shfl_xor(ssum, 32);
      float attn = e * __builtin_amdgcn_rcpf(ssum);
      f32x4 av4 = {attn, attn, attn, attn};
      f32x2 av2 = {attn, attn};

      oa0123 += av4 * s0123;
      oa45   += av2 * s45;
    }

    // p-reduction (once per (t,h)), fold 1/T at store
    float o0 = oa0123.x, o1 = oa0123.y, o2 = oa0123.z, o3 = oa0123.w;
    float o4 = oa45.x, o5 = oa45.y;
    o0 += __shfl_xor(o0, 8); o0 += __shfl_xor(o0, 16); o0 += __shfl_xor(o0, 32);
    o1 += __shfl_xor(o1, 8); o1 += __shfl_xor(o1, 16); o1 += __shfl_xor(o1, 32);
    o2 += __shfl_xor(o2, 8); o2 += __shfl_xor(o2, 16); o2 += __shfl_xor(o2, 32);
    o3 += __shfl_xor(o3, 8); o3 += __shfl_xor(o3, 16); o3 += __shfl_xor(o3, 32);
    o4 += __shfl_xor(o4, 8); o4 += __shfl_xor(o4, 16); o4 += __shfl_xor(o4, 32);
    o5 += __shfl_xor(o5, 8); o5 += __shfl_xor(o5, 16); o5 += __shfl_xor(o5, 32);

    if (p == 0) {
      __hip_bfloat16* outp = O1 + row * C_ + h * HD_ + 6 * k;
      unsigned* u = (unsigned*)outp;
      u[0] = (unsigned)bf16_bits(o0 * 0.125f) | ((unsigned)bf16_bits(o1 * 0.125f) << 16);
      u[1] = (unsigned)bf16_bits(o2 * 0.125f) | ((unsigned)bf16_bits(o3 * 0.125f) << 16);
      u[2] = (unsigned)bf16_bits(o4 * 0.125f) | ((unsigned)bf16_bits(o5 * 0.125f) << 16);
    }
  }
}

// ---------------------------------------------------------------------------
extern "C" void kernel_launch(void* const* d_in, const int* in_sizes, int n_in,
                              void* d_out, int out_size, void* d_ws, size_t ws_size,
                              hipStream_t stream) {
  const float* f    = (const float*)d_in[0];
  const float* Wq   = (const float*)d_in[1];
  const float* bq   = (const float*)d_in[2];
  const float* Woff = (const float*)d_in[3];
  const float* boff = (const float*)d_in[4];
  const float* Wout = (const float*)d_in[5];
  const float* bout = (const float*)d_in[6];
  float* outp = (float*)d_out;

  // workspace layout (~79 MB):
  //   Qb   bf16 [M,384]    16.8 MB
  //   OFFb fp32 [M,128]    11.2 MB
  //   ft   fp32 [B,N,T,C]  33.6 MB
  //   A16  bf16 [M,384]    16.8 MB  (O1 aliases A16 after GEMM1)
  //   Wt / Wot bf16         0.7 MB
  __hip_bfloat16* Qb = (__hip_bfloat16*)d_ws;
  float* OFFb = (float*)(Qb + (size_t)M_ * C_);
  float* ft   = OFFb + (size_t)M_ * 128;
  __hip_bfloat16* A16 = (__hip_bfloat16*)(ft + (size_t)B_ * N_ * T_ * C_);
  __hip_bfloat16* O1  = A16;   // alias: A16 dead after GEMM1, O1 written by attend
  __hip_bfloat16* Wt  = A16 + (size_t)M_ * C_;
  __hip_bfloat16* Wot = Wt + (size_t)512 * 384;

  dim3 blk(256);

  cast_transpose_kernel<<<dim3(B_ * N_), blk, 0, stream>>>(f, A16, ft);
  prep_w_kernel<<<dim3(896), blk, 0, stream>>>(Wq, Woff, Wout, Wt, Wot);

  // fused q+off GEMM: [M,384] @ [384,512] -> Qb (bf16, x log2e/sqrt(48)) / OFFb
  mfma_gemm_kernel<<<dim3((M_ + 127) / 128, 4), blk, 0, stream>>>(
      A16, Wt, bq, boff, nullptr, Qb, OFFb, 1, 0.20822825268806912f);

  attend_kernel<<<dim3(B_ * N_ * 2), blk, 0, stream>>>(ft, Qb, OFFb, O1);

  // output GEMM: [M,384] @ [384,384] -> outp
  mfma_gemm_kernel<<<dim3((M_ + 127) / 128, 3), blk, 0, stream>>>(
      O1, Wot, bout, nullptr, outp, nullptr, nullptr, 0, 1.0f);
}

// Round 10
// 322.972 us; speedup vs baseline: 1.4819x; 1.4819x over previous
//
#include <hip/hip_runtime.h>
#include <hip/hip_bf16.h>
#include <hip/hip_fp16.h>
#include <cstddef>

// Problem constants
constexpr int B_  = 2;
constexpr int T_  = 8;
constexpr int HW_ = 37;          // H == W == 37
constexpr int N_  = HW_ * HW_;   // 1369
constexpr int C_  = 384;
constexpr int NH_ = 8;
constexpr int MP_ = 8;
constexpr int HD_ = C_ / NH_;    // 48
constexpr int M_  = B_ * T_ * N_; // 21904

typedef short bf16x8 __attribute__((ext_vector_type(8)));
typedef float f32x4 __attribute__((ext_vector_type(4)));
typedef float f32x2 __attribute__((ext_vector_type(2)));
typedef _Float16 h16x2 __attribute__((ext_vector_type(2)));
typedef unsigned u32x3 __attribute__((ext_vector_type(3)));
typedef u32x3 uau32x3 __attribute__((aligned(4)));

static __device__ __forceinline__ unsigned short bf16_bits(float v) {
  __hip_bfloat16 b = __float2bfloat16(v);
  return *reinterpret_cast<unsigned short*>(&b);
}

static __device__ __forceinline__ h16x2 bch2(unsigned u) {
  return __builtin_bit_cast(h16x2, u);
}

// ---------------------------------------------------------------------------
// Fused cast + transpose. One pass over f (fp32 [B,T,N,C]):
//   A16[b][t][n][c] = bf16(f)      (same layout, feeds GEMM1)
//   ft [b][n][t][c] = fp16(f)      (T adjacent to C, feeds attend)
// ---------------------------------------------------------------------------
__global__ __launch_bounds__(256)
void cast_transpose_kernel(const float* __restrict__ f,
                           __hip_bfloat16* __restrict__ A16,
                           _Float16* __restrict__ ft) {
  const int bn = blockIdx.x;          // b*N + n
  const int n = bn % N_;
  const int b = bn / N_;
  const size_t dst_base = (size_t)bn * (T_ * C_);
#pragma unroll
  for (int i = 0; i < 12; ++i) {      // 12*256 = 3072 = T*C
    int idx = i * 256 + threadIdx.x;  // t*C + c
    int t = idx / C_;
    int c = idx - t * C_;
    size_t src = ((size_t)(b * T_ + t) * N_ + n) * C_ + c;
    float v = f[src];
    ft[dst_base + idx] = (_Float16)v;
    A16[src] = __float2bfloat16(v);
  }
}

// ---------------------------------------------------------------------------
// Pre-transpose weights to [N][K] bf16.
// ---------------------------------------------------------------------------
__global__ __launch_bounds__(256)
void prep_w_kernel(const float* __restrict__ Wq, const float* __restrict__ Woff,
                   const float* __restrict__ Wout,
                   __hip_bfloat16* __restrict__ Wt, __hip_bfloat16* __restrict__ Wot) {
  int nrow = blockIdx.x;           // 0..895
  if (nrow < 512) {
    const float* src; int col, ld;
    if (nrow < 384) { src = Wq; col = nrow; ld = 384; }
    else            { src = Woff; col = nrow - 384; ld = 128; }
    for (int k = threadIdx.x; k < 384; k += 256)
      Wt[(size_t)nrow * 384 + k] = __float2bfloat16(src[(size_t)k * ld + col]);
  } else {
    int col = nrow - 512;
    for (int k = threadIdx.x; k < 384; k += 256)
      Wot[(size_t)col * 384 + k] = __float2bfloat16(Wout[(size_t)k * 384 + col]);
  }
}

// ---------------------------------------------------------------------------
// bf16 MFMA GEMM: acc = A[M,384] @ Wt[N,384]^T + bias, scaled by out0_scale.
// split=1 (GEMM1): N=512; cols<384 -> out0h (fp16, scaled), cols>=384 -> out1 (fp32).
// split=0 (GEMM2): out0 (fp32).
// ---------------------------------------------------------------------------
__global__ __launch_bounds__(256)
void mfma_gemm_kernel(const __hip_bfloat16* __restrict__ A,
                      const __hip_bfloat16* __restrict__ Wt,
                      const float* __restrict__ b0, const float* __restrict__ b1,
                      float* __restrict__ out0, _Float16* __restrict__ out0h,
                      float* __restrict__ out1,
                      int split, float out0_scale) {
  __shared__ __hip_bfloat16 As[128][40];
  __shared__ __hip_bfloat16 Bs[128][40];
  const int m0 = blockIdx.x * 128;
  const int n0 = blockIdx.y * 128;
  const int tid = threadIdx.x;
  const int wv = tid >> 6, lane = tid & 63;
  const int wr = wv >> 1, wc = wv & 1;
  const int lr = lane & 15, kg = lane >> 4;

  f32x4 acc[4][4] = {};

  for (int k0 = 0; k0 < 384; k0 += 32) {
#pragma unroll
    for (int u = 0; u < 2; ++u) {
      int c = tid + u * 256;
      int row = c >> 2;
      int off = (c & 3) * 8;
      int gm = m0 + row;
      uint4 va = make_uint4(0u, 0u, 0u, 0u);
      if (gm < M_) va = *(const uint4*)(A + (size_t)gm * 384 + k0 + off);
      *(uint4*)&As[row][off] = va;
      uint4 vb = *(const uint4*)(Wt + (size_t)(n0 + row) * 384 + k0 + off);
      *(uint4*)&Bs[row][off] = vb;
    }
    __syncthreads();

    bf16x8 af[4], bfr[4];
#pragma unroll
    for (int i = 0; i < 4; ++i)
      af[i] = *(const bf16x8*)&As[wr * 64 + i * 16 + lr][kg * 8];
#pragma unroll
    for (int i = 0; i < 4; ++i)
      bfr[i] = *(const bf16x8*)&Bs[wc * 64 + i * 16 + lr][kg * 8];

#pragma unroll
    for (int mi = 0; mi < 4; ++mi)
#pragma unroll
      for (int ni = 0; ni < 4; ++ni)
        acc[mi][ni] = __builtin_amdgcn_mfma_f32_16x16x32_bf16(
            af[mi], bfr[ni], acc[mi][ni], 0, 0, 0);
    __syncthreads();
  }

  const int mrow = (lane >> 4) * 4;
#pragma unroll
  for (int mi = 0; mi < 4; ++mi) {
#pragma unroll
    for (int ni = 0; ni < 4; ++ni) {
#pragma unroll
      for (int j = 0; j < 4; ++j) {
        int gm = m0 + wr * 64 + mi * 16 + mrow + j;
        int gn = n0 + wc * 64 + ni * 16 + lr;
        if (gm >= M_) continue;
        float v = acc[mi][ni][j];
        if (!split) {
          out0[(size_t)gm * 384 + gn] = (v + b0[gn]) * out0_scale;
        } else {
          if (gn < 384) out0h[(size_t)gm * 384 + gn] =
              (_Float16)((v + b0[gn]) * out0_scale);
          else          out1[(size_t)gm * 128 + (gn - 384)] = v + b1[gn - 384];
        }
      }
    }
  }
}

// ---------------------------------------------------------------------------
// Deformable attention core — fp16 ft/Q, packed-fp16 blend + v_dot2 logits.
// Grid = (bn, head-quad) = 5476 blocks (XCD-chunked bijective swizzle);
// 4 waves/block, ONE head per wave, t-loop inside (L2 reuse of ft).
// Lane role: p = lane>>3 (point), k = lane&7 (channel slice d = 6k..6k+5).
// Per r: 4 dwordx3 loads, 12 pk_fma_f16 blend, 3 fdot2 logit, 6 mix-fma PV.
// Tap pointers centered at r=3: imm offsets -2304..+3072 B (13-bit signed ok).
// log2e/sqrt(48) folded into Q upstream; 1/T folded into final store.
// ---------------------------------------------------------------------------
__global__ __launch_bounds__(256)
void attend_kernel(const _Float16* __restrict__ ft,
                   const _Float16* __restrict__ Qh,
                   const float* __restrict__ OFF,
                   __hip_bfloat16* __restrict__ O1) {
  // bijective chunked XCD swizzle over grid of B*N*2 = 5476 blocks
  const int grid = B_ * N_ * 2;
  const int q8 = grid / 8, r8 = grid % 8;
  int c = blockIdx.x & 7, j = blockIdx.x >> 3;
  int id = (c < r8) ? c * (q8 + 1) + j : r8 * (q8 + 1) + (c - r8) * q8 + j;
  const int hq = id & 1;
  const int bn = id >> 1;

  const int n = bn % N_;
  const int b = bn / N_;
  const int w    = threadIdx.x >> 6;
  const int h    = hq * 4 + w;          // one head per wave
  const int lane = threadIdx.x & 63;
  const int p = lane >> 3;
  const int k = lane & 7;
  const float cy = (float)(n / HW_);
  const float cx = (float)(n % HW_);
  const int bnb = b * N_;
  const int chb = h * HD_ + 6 * k;

  for (int t = 0; t < T_; ++t) {
    const size_t row = (size_t)(b * T_ + t) * N_ + n;

    // q fragment (fp16, pre-scaled by log2e/sqrt(48) in GEMM epilogue)
    uau32x3 qw = *(const uau32x3*)(Qh + row * C_ + h * HD_ + 6 * k);
    h16x2 q01 = bch2(qw.x), q23 = bch2(qw.y), q45 = bch2(qw.z);

    // bilinear taps for my point p
    const float* op = OFF + row * (NH_ * MP_ * 2) + h * (MP_ * 2) + p * 2;
    float y = cy + op[0];
    float x = cx + op[1];
    float y0f = floorf(y), x0f = floorf(x);
    float wy = y - y0f, wx = x - x0f;
    int y0 = (int)y0f, x0 = (int)x0f;
    int y1 = y0 + 1, x1 = x0 + 1;
    float vy0 = (y0 >= 0 && y0 < HW_) ? 1.f : 0.f;
    float vy1 = (y1 >= 0 && y1 < HW_) ? 1.f : 0.f;
    float vx0 = (x0 >= 0 && x0 < HW_) ? 1.f : 0.f;
    float vx1 = (x1 >= 0 && x1 < HW_) ? 1.f : 0.f;
    int cy0 = min(max(y0, 0), HW_ - 1), cy1 = min(max(y1, 0), HW_ - 1);
    int cx0 = min(max(x0, 0), HW_ - 1), cx1 = min(max(x1, 0), HW_ - 1);
    float tw0 = (1.f - wy) * (1.f - wx) * vy0 * vx0;
    float tw1 = (1.f - wy) * wx * vy0 * vx1;
    float tw2 = wy * (1.f - wx) * vy1 * vx0;
    float tw3 = wy * wx * vy1 * vx1;
    _Float16 t0h = (_Float16)tw0, t1h = (_Float16)tw1;
    _Float16 t2h = (_Float16)tw2, t3h = (_Float16)tw3;
    h16x2 tw0h = {t0h, t0h}, tw1h = {t1h, t1h};
    h16x2 tw2h = {t2h, t2h}, tw3h = {t3h, t3h};

    // tap bases centered at r=3 (all unrolled r offsets fold into load imm)
    const _Float16* tp0 = ft + ((bnb + cy0 * HW_ + cx0) * T_ + 3) * C_ + chb;
    const _Float16* tp1 = ft + ((bnb + cy0 * HW_ + cx1) * T_ + 3) * C_ + chb;
    const _Float16* tp2 = ft + ((bnb + cy1 * HW_ + cx0) * T_ + 3) * C_ + chb;
    const _Float16* tp3 = ft + ((bnb + cy1 * HW_ + cx1) * T_ + 3) * C_ + chb;

    float o0 = 0.f, o1 = 0.f, o2 = 0.f, o3 = 0.f, o4 = 0.f, o5 = 0.f;

#pragma unroll
    for (int r = 0; r < T_; ++r) {
      const int roff = (r - 3) * C_;
      uau32x3 ua = *(const uau32x3*)(tp0 + roff);
      uau32x3 ub = *(const uau32x3*)(tp1 + roff);
      uau32x3 uc = *(const uau32x3*)(tp2 + roff);
      uau32x3 ud = *(const uau32x3*)(tp3 + roff);

      // packed fp16 bilinear blend (v_pk_fma_f16)
      h16x2 s01 = bch2(ua.x) * tw0h + bch2(ub.x) * tw1h + bch2(uc.x) * tw2h + bch2(ud.x) * tw3h;
      h16x2 s23 = bch2(ua.y) * tw0h + bch2(ub.y) * tw1h + bch2(uc.y) * tw2h + bch2(ud.y) * tw3h;
      h16x2 s45 = bch2(ua.z) * tw0h + bch2(ub.z) * tw1h + bch2(uc.z) * tw2h + bch2(ud.z) * tw3h;

      // logit: v_dot2_f32_f16 chain (f32 accumulate), then k-group reduce
      float lg = __builtin_amdgcn_fdot2(q01, s01,
                 __builtin_amdgcn_fdot2(q23, s23,
                 __builtin_amdgcn_fdot2(q45, s45, 0.f, false), false), false);
      lg += __shfl_xor(lg, 1);
      lg += __shfl_xor(lg, 2);
      lg += __shfl_xor(lg, 4);

      // point-count mask for this (t, r)
      int dd = t - r; dd = dd < 0 ? -dd : dd;
      int npts = (56 - 8 * dd) / 7; npts = npts < 1 ? 1 : npts;

      // softmax over p without max-sub (logits O(1); masked -> 0)
      float e = (p < npts) ? exp2f(lg) : 0.f;
      float ssum = e;
      ssum += __shfl_xor(ssum, 8);
      ssum += __shfl_xor(ssum, 16);
      ssum += __shfl_xor(ssum, 32);
      float attn = e * __builtin_amdgcn_rcpf(ssum);

      // PV: f32 accumulate from fp16 s (v_fma_mix_f32)
      o0 = fmaf((float)s01.x, attn, o0);
      o1 = fmaf((float)s01.y, attn, o1);
      o2 = fmaf((float)s23.x, attn, o2);
      o3 = fmaf((float)s23.y, attn, o3);
      o4 = fmaf((float)s45.x, attn, o4);
      o5 = fmaf((float)s45.y, attn, o5);
    }

    // p-reduction (once per (t,h)), fold 1/T at store
    o0 += __shfl_xor(o0, 8); o0 += __shfl_xor(o0, 16); o0 += __shfl_xor(o0, 32);
    o1 += __shfl_xor(o1, 8); o1 += __shfl_xor(o1, 16); o1 += __shfl_xor(o1, 32);
    o2 += __shfl_xor(o2, 8); o2 += __shfl_xor(o2, 16); o2 += __shfl_xor(o2, 32);
    o3 += __shfl_xor(o3, 8); o3 += __shfl_xor(o3, 16); o3 += __shfl_xor(o3, 32);
    o4 += __shfl_xor(o4, 8); o4 += __shfl_xor(o4, 16); o4 += __shfl_xor(o4, 32);
    o5 += __shfl_xor(o5, 8); o5 += __shfl_xor(o5, 16); o5 += __shfl_xor(o5, 32);

    if (p == 0) {
      __hip_bfloat16* outp = O1 + row * C_ + h * HD_ + 6 * k;
      unsigned* u = (unsigned*)outp;
      u[0] = (unsigned)bf16_bits(o0 * 0.125f) | ((unsigned)bf16_bits(o1 * 0.125f) << 16);
      u[1] = (unsigned)bf16_bits(o2 * 0.125f) | ((unsigned)bf16_bits(o3 * 0.125f) << 16);
      u[2] = (unsigned)bf16_bits(o4 * 0.125f) | ((unsigned)bf16_bits(o5 * 0.125f) << 16);
    }
  }
}

// ---------------------------------------------------------------------------
extern "C" void kernel_launch(void* const* d_in, const int* in_sizes, int n_in,
                              void* d_out, int out_size, void* d_ws, size_t ws_size,
                              hipStream_t stream) {
  const float* f    = (const float*)d_in[0];
  const float* Wq   = (const float*)d_in[1];
  const float* bq   = (const float*)d_in[2];
  const float* Woff = (const float*)d_in[3];
  const float* boff = (const float*)d_in[4];
  const float* Wout = (const float*)d_in[5];
  const float* bout = (const float*)d_in[6];
  float* outp = (float*)d_out;

  // workspace layout (~62 MB):
  //   Qh   fp16 [M,384]    16.8 MB
  //   OFFb fp32 [M,128]    11.2 MB
  //   ft   fp16 [B,N,T,C]  16.8 MB
  //   A16  bf16 [M,384]    16.8 MB  (O1 aliases A16 after GEMM1)
  //   Wt / Wot bf16         0.7 MB
  _Float16* Qh = (_Float16*)d_ws;
  float* OFFb = (float*)(Qh + (size_t)M_ * C_);
  _Float16* ft = (_Float16*)(OFFb + (size_t)M_ * 128);
  __hip_bfloat16* A16 = (__hip_bfloat16*)(ft + (size_t)B_ * N_ * T_ * C_);
  __hip_bfloat16* O1  = A16;   // alias: A16 dead after GEMM1, O1 written by attend
  __hip_bfloat16* Wt  = A16 + (size_t)M_ * C_;
  __hip_bfloat16* Wot = Wt + (size_t)512 * 384;

  dim3 blk(256);

  cast_transpose_kernel<<<dim3(B_ * N_), blk, 0, stream>>>(f, A16, ft);
  prep_w_kernel<<<dim3(896), blk, 0, stream>>>(Wq, Woff, Wout, Wt, Wot);

  // fused q+off GEMM: [M,384] @ [384,512] -> Qh (fp16, x log2e/sqrt(48)) / OFFb
  mfma_gemm_kernel<<<dim3((M_ + 127) / 128, 4), blk, 0, stream>>>(
      A16, Wt, bq, boff, nullptr, Qh, OFFb, 1, 0.20822825268806912f);

  attend_kernel<<<dim3(B_ * N_ * 2), blk, 0, stream>>>(ft, Qh, OFFb, O1);

  // output GEMM: [M,384] @ [384,384] -> outp
  mfma_gemm_kernel<<<dim3((M_ + 127) / 128, 3), blk, 0, stream>>>(
      O1, Wot, bout, nullptr, outp, nullptr, nullptr, 0, 1.0f);
}